// Round 10
// baseline (104.778 us; speedup 1.0000x reference)
//
#include <hip/hip_runtime.h>
#include <hip/hip_bf16.h>
#include <stdint.h>

#define ALPHA 0.2f

typedef __attribute__((ext_vector_type(8))) short bf16x8;
typedef __attribute__((ext_vector_type(4))) float f32x4;

__device__ __forceinline__ short f2bf(float f) {
    union { float f; uint32_t u; } c; c.f = f;
    uint32_t u = c.u + 0x7FFF + ((c.u >> 16) & 1);   // round-to-nearest-even
    return (short)(u >> 16);
}

// pack two fp32 -> packed bf16 pair (round-half-up)
__device__ __forceinline__ uint32_t pk_bf16(float lo, float hi) {
    union { float f; uint32_t u; } a, b;
    a.f = lo; b.f = hi;
    return __builtin_amdgcn_perm(b.u + 0x8000u, a.u + 0x8000u, 0x07060302u);
}

// ---------------------------------------------------------------------------
// Kernel 0: pack adj into byte-masks (8 ints -> 1 byte per thread). First 64
// blocks also pre-transpose W (fp32 [k][f]) -> WTg (bf16 [f][k]).
// ---------------------------------------------------------------------------
__global__ __launch_bounds__(256) void pack_adj_kernel(
        const int* __restrict__ adj, uint8_t* __restrict__ bytes,
        const float* __restrict__ W, short* __restrict__ WTg) {
    int t = blockIdx.x * 256 + threadIdx.x;            // 524288 threads
    const int4* a4 = reinterpret_cast<const int4*>(adj) + (size_t)t * 2;
    int4 x0 = a4[0], x1 = a4[1];
    uint32_t m = 0;
    m |= (x0.x > 0) ? 1u   : 0u;  m |= (x0.y > 0) ? 2u   : 0u;
    m |= (x0.z > 0) ? 4u   : 0u;  m |= (x0.w > 0) ? 8u   : 0u;
    m |= (x1.x > 0) ? 16u  : 0u;  m |= (x1.y > 0) ? 32u  : 0u;
    m |= (x1.z > 0) ? 64u  : 0u;  m |= (x1.w > 0) ? 128u : 0u;
    bytes[t] = (uint8_t)m;

    if (blockIdx.x < 64) {
        int idx = blockIdx.x * 256 + threadIdx.x;
        int k = idx >> 7, f = idx & 127;
        WTg[f * 128 + k] = f2bf(W[k * 128 + f]);
    }
}

// ---------------------------------------------------------------------------
// Kernel 1 (v19): Wh = h @ W, 32 rows/block via 2 sequential 16-row tiles
// (structure correctness-proven in the round-6 fused phase 1). Grid 512:
// halves WTg L2 re-reads and block count vs the 16-row version.
// s1/s2 pre-scaled by log2(e) so attn uses v_exp_f32 (exp2) directly.
// ---------------------------------------------------------------------------
__global__ __launch_bounds__(256) void wh_kernel(
        const float* __restrict__ h, const short* __restrict__ WTg,
        const float* __restrict__ a, short* __restrict__ whT,
        float* __restrict__ s1g, float* __restrict__ s2g) {
    __shared__ float sred[4][2][16];
    __shared__ short tr[4][32][24];

    int tid = threadIdx.x, wid = tid >> 6, lane = tid & 63;
    int q = lane >> 4, n = lane & 15;
    int bb = blockIdx.x & 7;                           // XCD-local batch
    int tile0 = blockIdx.x >> 3;                       // 0..63

    #pragma unroll
    for (int t2 = 0; t2 < 2; ++t2) {
        if (t2) __syncthreads();                       // sred/tr reuse hazard
        int tile = tile0 + t2 * 64;                    // 0..127
        int rb = bb * 2048 + tile * 16;                // global row base
        int row = rb + n;

        f32x4 acc[2] = {};
        #pragma unroll
        for (int kc = 0; kc < 4; ++kc) {
            const float* hp = h + (size_t)row * 128 + kc * 32 + q * 8;
            float4 h0 = reinterpret_cast<const float4*>(hp)[0];
            float4 h1 = reinterpret_cast<const float4*>(hp)[1];
            bf16x8 afrag;
            afrag[0] = f2bf(h0.x); afrag[1] = f2bf(h0.y);
            afrag[2] = f2bf(h0.z); afrag[3] = f2bf(h0.w);
            afrag[4] = f2bf(h1.x); afrag[5] = f2bf(h1.y);
            afrag[6] = f2bf(h1.z); afrag[7] = f2bf(h1.w);
            #pragma unroll
            for (int u = 0; u < 2; ++u) {
                int t = wid * 2 + u;
                bf16x8 bfrag = *reinterpret_cast<const bf16x8*>(
                    WTg + (t * 16 + n) * 128 + kc * 32 + q * 8);
                acc[u] = __builtin_amdgcn_mfma_f32_16x16x32_bf16(afrag, bfrag, acc[u], 0, 0, 0);
            }
        }

        float p1[4] = {0.f, 0.f, 0.f, 0.f}, p2[4] = {0.f, 0.f, 0.f, 0.f};
        #pragma unroll
        for (int u = 0; u < 2; ++u) {
            int c = (wid * 2 + u) * 16 + n;
            float a1c = a[c] * 1.442695041f;           // fold log2(e) into s1
            float a2c = a[128 + c] * 1.442695041f;     // and s2
            #pragma unroll
            for (int r = 0; r < 4; ++r) {
                p1[r] += acc[u][r] * a1c;
                p2[r] += acc[u][r] * a2c;
            }
        }
        #pragma unroll
        for (int d = 1; d < 16; d <<= 1) {
            #pragma unroll
            for (int r = 0; r < 4; ++r) {
                p1[r] += __shfl_xor(p1[r], d);
                p2[r] += __shfl_xor(p2[r], d);
            }
        }
        if (n == 0) {
            #pragma unroll
            for (int r = 0; r < 4; ++r) {
                sred[wid][0][q * 4 + r] = p1[r];
                sred[wid][1][q * 4 + r] = p2[r];
            }
        }

        #pragma unroll
        for (int u = 0; u < 2; ++u)
            #pragma unroll
            for (int r = 0; r < 4; ++r)
                tr[wid][u * 16 + n][q * 4 + r] = f2bf(acc[u][r]);
        __syncthreads();

        if (wid == 0 && lane < 16) {
            float v1 = 0.f, v2 = 0.f;
            #pragma unroll
            for (int v = 0; v < 4; ++v) { v1 += sred[v][0][lane]; v2 += sred[v][1][lane]; }
            s1g[rb + lane] = v1;
            s2g[rb + lane] = v2;
        }

        int jr = rb & 2047;
        int fl = lane & 31, jh = lane >> 5;
        bf16x8 v = *reinterpret_cast<const bf16x8*>(&tr[wid][fl][jh * 8]);
        int f = wid * 32 + fl;
        int t = f >> 4, nn = f & 15;
        int jc = jr >> 5;
        int qg = ((jr & 31) >> 3) + jh;                // jo>>3 for this 8-run
        *reinterpret_cast<bf16x8*>(
            whT + (size_t)(bb * 64 + jc) * 4096 + t * 512 + qg * 128 + nn * 8) = v;
    }
}

// ---------------------------------------------------------------------------
// Kernel 2 (v20): v18 main loop untouched (direct-from-L2, dual-row-group
// waves, 4-way j-split, no main-loop barriers). Distributed epilogue with
// the FINISH call-site fix: K varies 0..3 per wave, TBASE constant per wave
// (v19 passed the final t as TBASE while the macro adds K -> t was 2K).
// Wave w owns slices s in [4w,4w+4): w0/w1 rowgroup0 t0-3/t4-7, w2/w3
// rowgroup1 t0-3/t4-7. ONE barrier, 4x parallel combine+store.
// ---------------------------------------------------------------------------
__device__ __forceinline__ void load_nb(const char* gb, int chunk, int lane,
                                        bf16x8* nb) {
    const char* cb = gb + (size_t)chunk * 8192 + lane * 16;
    #pragma unroll
    for (int t = 0; t < 8; ++t)
        nb[t] = *reinterpret_cast<const bf16x8*>(cb + t * 1024);
}

__global__ __launch_bounds__(256, 2) void attn_kernel(
        const short* __restrict__ whT, const float* __restrict__ s1g,
        const float* __restrict__ s2g, const uint8_t* __restrict__ adjb,
        float* __restrict__ out) {
    __shared__ uint32_t mlds[32 * 65];                 // 8.32 KB masks
    __shared__ float s2lds[2048];                      // 8 KB s2
    __shared__ float dslds[4][2][16];                  // per-wave denominators
    __shared__ f32x4 cbuf[4][12][64];                  // 48 KB combine buffer

    int tid = threadIdx.x, wid = tid >> 6, lane = tid & 63;
    int q = lane >> 4, n = lane & 15;
    int b  = blockIdx.x & 7;                           // XCD-local batch
    int ib = (blockIdx.x >> 3) * 32;                   // i-tile base (0..63)

    float s1A0 = s1g[b * 2048 + ib + n];               // row group 0 (rows 0-15)
    float s1A1 = s1g[b * 2048 + ib + 16 + n];          // row group 1 (rows 16-31)
    const char* gbase = reinterpret_cast<const char*>(whT) + (size_t)b * 524288;

    // ---- stage masks: 32 rows x 64 dwords, pitch 65
    {
        int r = tid >> 3, sub = tid & 7;
        const uint4* src = reinterpret_cast<const uint4*>(
            adjb + (size_t)(ib + r) * 256 + sub * 32);
        uint4 v0 = src[0], v1 = src[1];
        uint32_t* dst = &mlds[r * 65 + sub * 8];
        dst[0] = v0.x; dst[1] = v0.y; dst[2] = v0.z; dst[3] = v0.w;
        dst[4] = v1.x; dst[5] = v1.y; dst[6] = v1.z; dst[7] = v1.w;
    }
    // ---- stage s2 (2048 floats)
    {
        const float* s2b = s2g + b * 2048;
        float4 v0 = *reinterpret_cast<const float4*>(s2b + tid * 8);
        float4 v1 = *reinterpret_cast<const float4*>(s2b + tid * 8 + 4);
        *reinterpret_cast<float4*>(&s2lds[tid * 8])     = v0;
        *reinterpret_cast<float4*>(&s2lds[tid * 8 + 4]) = v1;
    }
    __syncthreads();                                   // masks/s2 visible

    f32x4 acc0[8] = {}, acc1[8] = {};
    float ds0 = 0.f, ds1 = 0.f;
    int gc0 = wid * 16;                                // this wave's chunk base
    int mrow0 = n * 65, mrow1 = (16 + n) * 65;

    bf16x8 nbA[8], nbB[8];
    load_nb(gbase, gc0, lane, nbA);

#define PROCESS(C, NB)                                                        \
    {                                                                         \
        int gc = gc0 + (C);                                                   \
        uint32_t mA0 = mlds[mrow0 + gc] >> (q * 8);                           \
        uint32_t mA1 = mlds[mrow1 + gc] >> (q * 8);                           \
        int sb = gc * 32 + q * 8;                                             \
        float4 s2a = *reinterpret_cast<const float4*>(&s2lds[sb]);            \
        float4 s2c = *reinterpret_cast<const float4*>(&s2lds[sb + 4]);        \
        float s2arr[8] = {s2a.x, s2a.y, s2a.z, s2a.w,                         \
                          s2c.x, s2c.y, s2c.z, s2c.w};                        \
        float p0[8], p1[8];                                                   \
        _Pragma("unroll")                                                     \
        for (int j = 0; j < 8; ++j) {                                         \
            float e0 = s1A0 + s2arr[j];                                       \
            e0 = fmaxf(e0, ALPHA * e0);                                       \
            float v0 = ((mA0 >> j) & 1) ? __builtin_amdgcn_exp2f(e0) : 0.0f;  \
            ds0 += v0; p0[j] = v0;                                            \
            float e1 = s1A1 + s2arr[j];                                       \
            e1 = fmaxf(e1, ALPHA * e1);                                       \
            float v1 = ((mA1 >> j) & 1) ? __builtin_amdgcn_exp2f(e1) : 0.0f;  \
            ds1 += v1; p1[j] = v1;                                            \
        }                                                                     \
        union { uint32_t u32[4]; bf16x8 v; } cv0, cv1;                        \
        _Pragma("unroll")                                                     \
        for (int pp = 0; pp < 4; ++pp) {                                      \
            cv0.u32[pp] = pk_bf16(p0[2 * pp], p0[2 * pp + 1]);                \
            cv1.u32[pp] = pk_bf16(p1[2 * pp], p1[2 * pp + 1]);                \
        }                                                                     \
        _Pragma("unroll")                                                     \
        for (int t = 0; t < 8; ++t) {                                         \
            acc0[t] = __builtin_amdgcn_mfma_f32_16x16x32_bf16(                \
                cv0.v, (NB)[t], acc0[t], 0, 0, 0);                            \
            acc1[t] = __builtin_amdgcn_mfma_f32_16x16x32_bf16(                \
                cv1.v, (NB)[t], acc1[t], 0, 0, 0);                            \
        }                                                                     \
    }

    #pragma unroll 1
    for (int cc = 0; cc < 16; cc += 2) {
        load_nb(gbase, gc0 + cc + 1, lane, nbB);       // prefetch odd chunk
        PROCESS(cc, nbA)
        if (cc + 2 < 16) load_nb(gbase, gc0 + cc + 2, lane, nbA);
        PROCESS(cc + 1, nbB)
    }
#undef PROCESS

    // ---- intra-wave denominators (sum over q; lane n holds full row-n part)
    ds0 += __shfl_xor(ds0, 16); ds0 += __shfl_xor(ds0, 32);
    ds1 += __shfl_xor(ds1, 16); ds1 += __shfl_xor(ds1, 32);
    if (q == 0) { dslds[wid][0][n] = ds0; dslds[wid][1][n] = ds1; }

    // ---- dump the 12 non-owned slices (slice s = rowgroup*8 + t; wave w
    // owns s in [4w, 4w+4)). Dump order: increasing s, skipping own range,
    // so slice s lands at index j = s - (s > 4w+3 ? 4 : 0).
    {
        int j = 0;
        #pragma unroll
        for (int s = 0; s < 16; ++s) {
            if ((s >> 2) != wid) {
                cbuf[wid][j][lane] = (s < 8) ? acc0[s] : acc1[s - 8];
                ++j;
            }
        }
    }
    __syncthreads();                                   // dumps + dslds visible

    // ---- each wave sums + normalizes + stores its 4 owned slices
    {
        int rgown = wid >> 1;                          // 0: rows 0-15, 1: 16-31
        float dtot = dslds[0][rgown][n] + dslds[1][rgown][n]
                   + dslds[2][rgown][n] + dslds[3][rgown][n];
        float rd[4];
        #pragma unroll
        for (int r = 0; r < 4; ++r)
            rd[r] = 1.0f / __shfl(dtot, q * 4 + r);

        size_t ob = ((size_t)b * 2048 + ib + rgown * 16) * 128;

#define FINISH(K, ACCARR, TBASE)                                              \
        {                                                                     \
            int s = wid * 4 + (K);                     /* owned slice */      \
            int t = (TBASE) + (K);                     /* t within rowgroup */\
            f32x4 v = (ACCARR)[t];                                            \
            _Pragma("unroll")                                                 \
            for (int w2 = 0; w2 < 4; ++w2) {                                  \
                if (w2 != wid) {                                              \
                    int j2 = s - (((s >> 2) > w2) ? 4 : 0);                   \
                    v += cbuf[w2][j2][lane];                                  \
                }                                                             \
            }                                                                 \
            _Pragma("unroll")                                                 \
            for (int r = 0; r < 4; ++r)                                       \
                out[ob + (size_t)(q * 4 + r) * 128 + t * 16 + n] = v[r] * rd[r]; \
        }

        // K = 0..3 within each wave; TBASE constant per wave (v19 bug fix:
        // previously the final t was passed as TBASE and K was added again).
        if (wid == 0) {
            FINISH(0, acc0, 0) FINISH(1, acc0, 0) FINISH(2, acc0, 0) FINISH(3, acc0, 0)
        } else if (wid == 1) {
            FINISH(0, acc0, 4) FINISH(1, acc0, 4) FINISH(2, acc0, 4) FINISH(3, acc0, 4)
        } else if (wid == 2) {
            FINISH(0, acc1, 0) FINISH(1, acc1, 0) FINISH(2, acc1, 0) FINISH(3, acc1, 0)
        } else {
            FINISH(0, acc1, 4) FINISH(1, acc1, 4) FINISH(2, acc1, 4) FINISH(3, acc1, 4)
        }
#undef FINISH
    }
}

// ---------------------------------------------------------------------------
extern "C" void kernel_launch(void* const* d_in, const int* in_sizes, int n_in,
                              void* d_out, int out_size, void* d_ws, size_t ws_size,
                              hipStream_t stream) {
    const float* h   = (const float*)d_in[0];   // [8][2048][128] f32
    const int*   adj = (const int*)d_in[1];     // [2048][2048] i32
    const float* W   = (const float*)d_in[2];   // [128][128] f32
    const float* a   = (const float*)d_in[3];   // [256][1] f32
    float* out = (float*)d_out;                 // [8][2048][128] f32

    char* ws = (char*)d_ws;
    short* whT = (short*)ws;                                  // 4 MB  bf16 whT (chunk-tiled)
    float* s1  = (float*)(ws + 4194304);                      // 64 KB
    float* s2  = (float*)(ws + 4259840);                      // 64 KB
    uint8_t* bytes = (uint8_t*)(ws + 4325376);                // 512 KB
    short* WTg = (short*)(ws + 4849664);                      // 32 KB bf16 W^T

    pack_adj_kernel<<<2048, 256, 0, stream>>>(adj, bytes, W, WTg);
    wh_kernel<<<512, 256, 0, stream>>>(h, WTg, a, whT, s1, s2);
    attn_kernel<<<512, 256, 0, stream>>>(whT, s1, s2, bytes, out);
}